// Round 6
// baseline (86.207 us; speedup 1.0000x reference)
//
#include <hip/hip_runtime.h>
#include <hip/hip_bf16.h>

typedef __attribute__((ext_vector_type(8))) short bf16x8;
typedef __attribute__((ext_vector_type(4))) float f32x4;
typedef unsigned short u16;

static __device__ __forceinline__ u16 f2bf(float f) {
  unsigned u = __builtin_bit_cast(unsigned, f);
  return (u16)((u + 0x7fffu + ((u >> 16) & 1u)) >> 16);
}

// ============ K1: Cb(1024x256 bf16) = bf16(x) @ Apre^T, Apre slice recomputed ==========
// grid (8,32): n0 = bx*32 (Cb cols / Apre rows), m0 = by*32 (rows).
// Stage 1: T1 slice (2 r1) + V1 full into LDS (trl_w-proven math).
// Stage 2: Apre rows [n0,n0+32) -> LDS Bs in K-major granules [kg(128)][q(32)][8 bf16]
//          (bank chunk = (q*4)&31 -> 16-lane ds_read_b128 is 2-way = free).
// Stage 3: 4-wave split-K GEMM (x f32 -> bf16 in-reg), LDS reduce, Cb store.
__global__ __launch_bounds__(256) void trl_g1(
    const float* __restrict__ x,
    const float* __restrict__ W0, const float* __restrict__ W1,
    const float* __restrict__ W2, const float* __restrict__ W3,
    u16* __restrict__ Cb) {
  __shared__ float S_T1[1024];      // [rr*512 + j1*32 + i1*4 + i0]
  __shared__ float S_V1[8192];      // [j3*512 + i3*128 + i2*16 + j1]
  __shared__ u16 Bs[128 * 32 * 8];  // 64 KB
  __shared__ float red[3][32 * 33];
  const int tid = threadIdx.x;
  const int n0 = blockIdx.x * 32;
  const int m0 = blockIdx.y * 32;
  const int r1a = n0 >> 4;

  // ---- stage 1 ----
  for (int k = 0; k < 4; ++k) {
    const int e = tid + 256 * k;
    const int i0 = e & 3, i1 = (e >> 2) & 7, j1 = (e >> 5) & 15, rr = e >> 9;
    float s = 0.f;
#pragma unroll
    for (int r0 = 0; r0 < 16; ++r0)
      s += W1[j1 * 128 + i1 * 16 + r0] * W0[(r0 * 16 + r1a + rr) * 4 + i0];
    S_T1[e] = s;
  }
  for (int k = 0; k < 32; ++k) {
    const int e = tid + 256 * k;
    const int j1 = e & 15, i2 = (e >> 4) & 7, i3 = (e >> 7) & 3, j3 = e >> 9;
    float s = 0.f;
#pragma unroll
    for (int j2 = 0; j2 < 16; ++j2)
      s += W3[j3 * 64 + i3 * 16 + j2] * W2[j2 * 128 + i2 * 16 + j1];
    S_V1[e] = s;
  }
  __syncthreads();

  // ---- stage 2: Apre slice ----
  for (int tau = 0; tau < 16; ++tau) {
    const int q = (tid & 7) + 8 * (tau >> 2);          // row (p = n0+q)
    const int grp = (tid >> 3) * 4 + (tau & 3);        // (i0,i1,gg)
    const int i0 = grp >> 5, i1 = (grp >> 2) & 7, gg = grp & 3;
    const int rr = q >> 4, j3 = q & 15;
    float tq[16];
#pragma unroll
    for (int j1 = 0; j1 < 16; ++j1) tq[j1] = S_T1[rr * 512 + j1 * 32 + i1 * 4 + i0];
    float a[8];
#pragma unroll
    for (int s = 0; s < 8; ++s) {
      const int i2 = gg * 2 + (s >> 2), i3 = s & 3;
      const float* vp = &S_V1[j3 * 512 + i3 * 128 + i2 * 16];
      float acc = 0.f;
#pragma unroll
      for (int j1 = 0; j1 < 16; ++j1) acc += tq[j1] * vp[j1];
      a[s] = acc;
    }
    bf16x8 w;
#pragma unroll
    for (int s = 0; s < 8; ++s) w[s] = (short)f2bf(a[s]);
    const int granule = i0 * 32 + i1 * 4 + gg;
    *(bf16x8*)&Bs[(granule * 32 + q) * 8] = w;
  }
  __syncthreads();

  // ---- stage 3: GEMM ----
  const int wave = tid >> 6, lane = tid & 63;
  const int l15 = lane & 15, l4 = lane >> 4;
  f32x4 acc[2][2] = {};
  const float* xr0 = x + (size_t)(m0 + l15) * 1024;
  const float* xr1 = x + (size_t)(m0 + 16 + l15) * 1024;
#pragma unroll
  for (int ks = 0; ks < 8; ++ks) {
    const int k = wave * 256 + ks * 32 + l4 * 8;
    const float4 f0 = *(const float4*)&xr0[k];
    const float4 f1 = *(const float4*)&xr0[k + 4];
    const float4 g0 = *(const float4*)&xr1[k];
    const float4 g1 = *(const float4*)&xr1[k + 4];
    bf16x8 a0, a1;
    a0[0] = (short)f2bf(f0.x); a0[1] = (short)f2bf(f0.y);
    a0[2] = (short)f2bf(f0.z); a0[3] = (short)f2bf(f0.w);
    a0[4] = (short)f2bf(f1.x); a0[5] = (short)f2bf(f1.y);
    a0[6] = (short)f2bf(f1.z); a0[7] = (short)f2bf(f1.w);
    a1[0] = (short)f2bf(g0.x); a1[1] = (short)f2bf(g0.y);
    a1[2] = (short)f2bf(g0.z); a1[3] = (short)f2bf(g0.w);
    a1[4] = (short)f2bf(g1.x); a1[5] = (short)f2bf(g1.y);
    a1[6] = (short)f2bf(g1.z); a1[7] = (short)f2bf(g1.w);
    const int kg = wave * 32 + ks * 4 + l4;
    const bf16x8 b0 = *(const bf16x8*)&Bs[(kg * 32 + l15) * 8];
    const bf16x8 b1 = *(const bf16x8*)&Bs[(kg * 32 + 16 + l15) * 8];
    acc[0][0] = __builtin_amdgcn_mfma_f32_16x16x32_bf16(a0, b0, acc[0][0], 0, 0, 0);
    acc[0][1] = __builtin_amdgcn_mfma_f32_16x16x32_bf16(a0, b1, acc[0][1], 0, 0, 0);
    acc[1][0] = __builtin_amdgcn_mfma_f32_16x16x32_bf16(a1, b0, acc[1][0], 0, 0, 0);
    acc[1][1] = __builtin_amdgcn_mfma_f32_16x16x32_bf16(a1, b1, acc[1][1], 0, 0, 0);
  }
  if (wave > 0) {
#pragma unroll
    for (int fm = 0; fm < 2; ++fm)
#pragma unroll
      for (int fn = 0; fn < 2; ++fn)
#pragma unroll
        for (int r = 0; r < 4; ++r)
          red[wave - 1][(fm * 16 + l4 * 4 + r) * 33 + fn * 16 + l15] = acc[fm][fn][r];
  }
  __syncthreads();
  if (wave == 0) {
#pragma unroll
    for (int fm = 0; fm < 2; ++fm)
#pragma unroll
      for (int fn = 0; fn < 2; ++fn)
#pragma unroll
        for (int r = 0; r < 4; ++r) {
          const int row = fm * 16 + l4 * 4 + r, col = fn * 16 + l15;
          float s = acc[fm][fn][r] + red[0][row * 33 + col] + red[1][row * 33 + col] +
                    red[2][row * 33 + col];
          Cb[(size_t)(m0 + row) * 256 + n0 + col] = f2bf(s);
        }
  }
}

// ============ K2: out(1024x1024 f32) = Cb @ Bmat^T + bias, Bmat slice recomputed =======
// grid (8,32): nb = bx*128 (out cols / Bmat rows), m0 = by*32.
// Stage 1: U1 4 slices + V2 full into LDS (trl_w-proven math).
// Stage 2: Bmat rows [nb,nb+128) -> LDS Bs [g(32)][ol(128)][8 bf16].
// Stage 3: each wave one 32x32 out tile (K=256), a from global Cb, b from LDS.
__global__ __launch_bounds__(256) void trl_g2(
    const u16* __restrict__ Cb,
    const float* __restrict__ W4, const float* __restrict__ W5,
    const float* __restrict__ W6, const float* __restrict__ W7,
    const float* __restrict__ bias,
    float* __restrict__ out) {
  __shared__ float S_U1[4 * 256];   // [cslot][j5l*16 + j3]
  __shared__ float S_V2[8192];      // [m7*2048 + r1*128 + j6h*16 + j5l]
  __shared__ u16 Bs[32 * 128 * 8];  // 64 KB
  const int tid = threadIdx.x;
  const int B7 = blockIdx.x;        // 0..7
  const int nb = B7 * 128;
  const int m0 = blockIdx.y * 32;
  const int kh = B7 >> 1;

  // ---- stage 1 ----
  for (int k = 0; k < 4; ++k) {
    const int j5l = tid >> 4, j3 = tid & 15;
    const int j5h = (4 * B7 + k) & 7;
    float s = 0.f;
#pragma unroll
    for (int kl = 0; kl < 16; ++kl)
      s += W5[(j5h * 16 + j5l) * 16 + kl] * W4[(kh * 16 + kl) * 16 + j3];
    S_U1[k * 256 + tid] = s;
  }
  for (int k = 0; k < 32; ++k) {
    const int e = tid + 256 * k;
    const int j5l = e & 15, j6h = (e >> 4) & 7, r1 = (e >> 7) & 15, m7 = e >> 11;
    float s = 0.f;
#pragma unroll
    for (int d = 0; d < 16; ++d)
      s += W7[m7 * 256 + r1 * 16 + d] * W6[(j6h * 16 + d) * 16 + j5l];
    S_V2[e] = s;
  }
  __syncthreads();

  // ---- stage 2: Bmat slice ----
  for (int tau = 0; tau < 16; ++tau) {
    const int ol = (tid & 7) + 8 * (tau & 7) + 64 * (tid >> 7);  // row (o = nb+ol)
    const int rj = ((tid >> 3) & 15) * 2 + (tau >> 3);
    const int r1 = rj >> 1, j3h = rj & 1;                        // cols r1*16+j3h*8 ..+7
    const int m7 = ol & 3, j6hd = (ol >> 2) & 3;
    const int j6h = ((ol >> 4) & 1) * 4 + j6hd;
    const int cslot = ol >> 5;
    const float* vp = &S_V2[((m7 * 16 + r1) * 8 + j6h) * 16];
    const float* up = &S_U1[cslot * 256 + j3h * 8];
    float a[8] = {};
#pragma unroll
    for (int j5l = 0; j5l < 16; ++j5l) {
      const float v = vp[j5l];
      const float* u = &up[j5l * 16];
#pragma unroll
      for (int s = 0; s < 8; ++s) a[s] += v * u[s];
    }
    bf16x8 w;
#pragma unroll
    for (int s = 0; s < 8; ++s) w[s] = (short)f2bf(a[s]);
    const int granule = r1 * 2 + j3h;
    *(bf16x8*)&Bs[(granule * 128 + ol) * 8] = w;
  }
  __syncthreads();

  // ---- stage 3: GEMM ----
  const int wave = tid >> 6, lane = tid & 63;
  const int l15 = lane & 15, l4 = lane >> 4;
  f32x4 acc[2][2] = {};
#pragma unroll
  for (int ks = 0; ks < 8; ++ks) {
    const int k = ks * 32 + l4 * 8;
    const bf16x8 a0 = *(const bf16x8*)&Cb[(size_t)(m0 + l15) * 256 + k];
    const bf16x8 a1 = *(const bf16x8*)&Cb[(size_t)(m0 + 16 + l15) * 256 + k];
    const int kg = ks * 4 + l4;
    const bf16x8 b0 = *(const bf16x8*)&Bs[(kg * 128 + wave * 32 + l15) * 8];
    const bf16x8 b1 = *(const bf16x8*)&Bs[(kg * 128 + wave * 32 + 16 + l15) * 8];
    acc[0][0] = __builtin_amdgcn_mfma_f32_16x16x32_bf16(a0, b0, acc[0][0], 0, 0, 0);
    acc[0][1] = __builtin_amdgcn_mfma_f32_16x16x32_bf16(a0, b1, acc[0][1], 0, 0, 0);
    acc[1][0] = __builtin_amdgcn_mfma_f32_16x16x32_bf16(a1, b0, acc[1][0], 0, 0, 0);
    acc[1][1] = __builtin_amdgcn_mfma_f32_16x16x32_bf16(a1, b1, acc[1][1], 0, 0, 0);
  }
#pragma unroll
  for (int fn = 0; fn < 2; ++fn) {
    const int gc = nb + wave * 32 + fn * 16 + l15;
    const float bv = bias[gc];
#pragma unroll
    for (int fm = 0; fm < 2; ++fm)
#pragma unroll
      for (int r = 0; r < 4; ++r) {
        const int gr = m0 + fm * 16 + l4 * 4 + r;
        out[(size_t)gr * 1024 + gc] = acc[fm][fn][r] + bv;
      }
  }
}

extern "C" void kernel_launch(void* const* d_in, const int* in_sizes, int n_in,
                              void* d_out, int out_size, void* d_ws, size_t ws_size,
                              hipStream_t stream) {
  const float* x  = (const float*)d_in[0];
  const float* W0 = (const float*)d_in[1];
  const float* W1 = (const float*)d_in[2];
  const float* W2 = (const float*)d_in[3];
  const float* W3 = (const float*)d_in[4];
  const float* W4 = (const float*)d_in[5];
  const float* W5 = (const float*)d_in[6];
  const float* W6 = (const float*)d_in[7];
  const float* W7 = (const float*)d_in[8];
  const float* bias = (const float*)d_in[9];

  char* ws = (char*)d_ws;
  u16* Cb = (u16*)ws;  // 512 KB (1024x256 bf16)
  float* outp = (float*)d_out;

  trl_g1<<<dim3(8, 32), 256, 0, stream>>>(x, W0, W1, W2, W3, Cb);
  trl_g2<<<dim3(8, 32), 256, 0, stream>>>(Cb, W4, W5, W6, W7, bias, outp);
}

// Round 7
// 33.680 us; speedup vs baseline: 2.5596x; 2.5596x over previous
//
#include <hip/hip_runtime.h>
#include <hip/hip_bf16.h>

typedef __attribute__((ext_vector_type(8))) short bf16x8;
typedef __attribute__((ext_vector_type(4))) float f32x4;
typedef unsigned short u16;

static __device__ __forceinline__ u16 f2bf(float f) {
  unsigned u = __builtin_bit_cast(unsigned, f);
  return (u16)((u + 0x7fffu + ((u >> 16) & 1u)) >> 16);
}

// ================= K1: weights -> Apre (256x1024 bf16), Bmat (1024x256 bf16) ==========
// Blocks 0..63 (type A): block b owns Apre rows p = 4b..4b+3
// Blocks 64..127 (type B): c = b-64 owns Bmat rows o = 16c..16c+15
// (round-3 proven body, unchanged)
__global__ __launch_bounds__(256) void trl_w(
    const float* __restrict__ W0, const float* __restrict__ W1,
    const float* __restrict__ W2, const float* __restrict__ W3,
    const float* __restrict__ W4, const float* __restrict__ W5,
    const float* __restrict__ W6, const float* __restrict__ W7,
    u16* __restrict__ Apre, u16* __restrict__ Bmat) {
  __shared__ float S1[512];
  __shared__ float S2[4096];
  const int tid = threadIdx.x;
  const int b = blockIdx.x;
  if (b < 64) {
    const int r1 = b >> 2;
    const int j3base = (b & 3) << 2;
#pragma unroll
    for (int e0 = 0; e0 < 512; e0 += 256) {
      const int e = e0 + tid;
      const int i0 = e & 3, i1 = (e >> 2) & 7, j1 = e >> 5;
      float s = 0.f;
#pragma unroll
      for (int r0 = 0; r0 < 16; ++r0)
        s += W1[j1 * 128 + i1 * 16 + r0] * W0[(r0 * 16 + r1) * 4 + i0];
      S1[e] = s;  // [j1*32 + i1*4 + i0]
    }
#pragma unroll
    for (int e0 = 0; e0 < 2048; e0 += 256) {
      const int e = e0 + tid;
      const int i3 = e & 3, pd = (e >> 2) & 3, j1 = (e >> 4) & 15, i2 = e >> 8;
      float s = 0.f;
#pragma unroll
      for (int j2 = 0; j2 < 16; ++j2)
        s += W3[(j3base + pd) * 64 + i3 * 16 + j2] * W2[j2 * 128 + i2 * 16 + j1];
      S2[e] = s;  // [i2*256 + j1*16 + pd*4 + i3]
    }
    __syncthreads();
    const int i0 = tid & 3, i1 = (tid >> 2) & 7, i2 = tid >> 5;
#pragma unroll
    for (int pd = 0; pd < 4; ++pd) {
      float a0 = 0.f, a1 = 0.f, a2 = 0.f, a3 = 0.f;
#pragma unroll
      for (int j1 = 0; j1 < 16; ++j1) {
        const float t = S1[j1 * 32 + i1 * 4 + i0];
        const float4 v = *(const float4*)&S2[i2 * 256 + j1 * 16 + pd * 4];
        a0 += t * v.x; a1 += t * v.y; a2 += t * v.z; a3 += t * v.w;
      }
      ushort4 o4;
      o4.x = f2bf(a0); o4.y = f2bf(a1); o4.z = f2bf(a2); o4.w = f2bf(a3);
      *(ushort4*)&Apre[(size_t)(4 * b + pd) * 1024 + i0 * 256 + i1 * 32 + i2 * 4] = o4;
    }
  } else {
    const int c = b - 64;
    const int kh = c >> 4, j5h = (c >> 1) & 7, j6hbase = (c & 1) << 2;
    {
      const int j5l = tid >> 4, j3 = tid & 15;
      float s = 0.f;
#pragma unroll
      for (int kl = 0; kl < 16; ++kl)
        s += W5[(j5h * 16 + j5l) * 16 + kl] * W4[(kh * 16 + kl) * 16 + j3];
      S1[tid] = s;  // [j5l*16 + j3]
    }
#pragma unroll
    for (int e0 = 0; e0 < 4096; e0 += 256) {
      const int e = e0 + tid;
      const int j5l = e & 15, j6hd = (e >> 4) & 3, r1 = (e >> 6) & 15, m7 = e >> 10;
      float s = 0.f;
#pragma unroll
      for (int d = 0; d < 16; ++d)
        s += W7[m7 * 256 + r1 * 16 + d] * W6[((j6hbase + j6hd) * 16 + d) * 16 + j5l];
      S2[e] = s;  // [((m7*16+r1)*4 + j6hd)*16 + j5l]
    }
    __syncthreads();
    const int r1 = (tid >> 2) & 15, j3q = tid & 3;
#pragma unroll
    for (int qq = 0; qq < 4; ++qq) {
      const int od = qq * 4 + (tid >> 6);
      const int m7 = od & 3, j6hd = od >> 2;
      float a0 = 0.f, a1 = 0.f, a2 = 0.f, a3 = 0.f;
#pragma unroll
      for (int j5l = 0; j5l < 16; ++j5l) {
        const float w = S2[((m7 * 16 + r1) * 4 + j6hd) * 16 + j5l];
        const float4 u = *(const float4*)&S1[j5l * 16 + j3q * 4];
        a0 += w * u.x; a1 += w * u.y; a2 += w * u.z; a3 += w * u.w;
      }
      ushort4 o4;
      o4.x = f2bf(a0); o4.y = f2bf(a1); o4.z = f2bf(a2); o4.w = f2bf(a3);
      *(ushort4*)&Bmat[(size_t)(16 * c + od) * 256 + r1 * 16 + j3q * 4] = o4;
    }
  }
}

// ============ K2: Cb(1024x256 bf16) = bf16(x) @ Apre^T (in-register cast) =============
// 256 blocks, XCD-swizzled: by (m-slab) = p&31, bx (n-chunk) = p>>5, so the 8 blocks
// sharing an x m-slab are p = by+32j => p mod 8 == by mod 8 -> same XCD -> x fetched
// from HBM once; Apre (512KB) L2-resident per XCD.
// Body: round-2-proven 32x32 tile, 4 waves split K=1024, LDS reduce.
__global__ __launch_bounds__(256) void trl_g1(const float* __restrict__ x,
                                              const u16* __restrict__ Apre,
                                              u16* __restrict__ Cb) {
  __shared__ float red[3][32 * 33];
  const int tid = threadIdx.x;
  const int wave = tid >> 6, lane = tid & 63;
  const int l15 = lane & 15, l4 = lane >> 4;
  const int p = blockIdx.x;
  const int m0 = (p & 31) * 32, n0 = (p >> 5) * 32;

  f32x4 acc[2][2] = {};
  const float* xr0 = x + (size_t)(m0 + l15) * 1024;
  const float* xr1 = x + (size_t)(m0 + 16 + l15) * 1024;
#pragma unroll
  for (int ks = 0; ks < 8; ++ks) {
    const int k = wave * 256 + ks * 32 + l4 * 8;
    const float4 f0 = *(const float4*)&xr0[k];
    const float4 f1 = *(const float4*)&xr0[k + 4];
    const float4 g0 = *(const float4*)&xr1[k];
    const float4 g1 = *(const float4*)&xr1[k + 4];
    bf16x8 a0, a1;
    a0[0] = (short)f2bf(f0.x); a0[1] = (short)f2bf(f0.y);
    a0[2] = (short)f2bf(f0.z); a0[3] = (short)f2bf(f0.w);
    a0[4] = (short)f2bf(f1.x); a0[5] = (short)f2bf(f1.y);
    a0[6] = (short)f2bf(f1.z); a0[7] = (short)f2bf(f1.w);
    a1[0] = (short)f2bf(g0.x); a1[1] = (short)f2bf(g0.y);
    a1[2] = (short)f2bf(g0.z); a1[3] = (short)f2bf(g0.w);
    a1[4] = (short)f2bf(g1.x); a1[5] = (short)f2bf(g1.y);
    a1[6] = (short)f2bf(g1.z); a1[7] = (short)f2bf(g1.w);
    const bf16x8 b0 = *(const bf16x8*)&Apre[(size_t)(n0 + l15) * 1024 + k];
    const bf16x8 b1 = *(const bf16x8*)&Apre[(size_t)(n0 + 16 + l15) * 1024 + k];
    acc[0][0] = __builtin_amdgcn_mfma_f32_16x16x32_bf16(a0, b0, acc[0][0], 0, 0, 0);
    acc[0][1] = __builtin_amdgcn_mfma_f32_16x16x32_bf16(a0, b1, acc[0][1], 0, 0, 0);
    acc[1][0] = __builtin_amdgcn_mfma_f32_16x16x32_bf16(a1, b0, acc[1][0], 0, 0, 0);
    acc[1][1] = __builtin_amdgcn_mfma_f32_16x16x32_bf16(a1, b1, acc[1][1], 0, 0, 0);
  }
  if (wave > 0) {
#pragma unroll
    for (int fm = 0; fm < 2; ++fm)
#pragma unroll
      for (int fn = 0; fn < 2; ++fn)
#pragma unroll
        for (int r = 0; r < 4; ++r)
          red[wave - 1][(fm * 16 + l4 * 4 + r) * 33 + fn * 16 + l15] = acc[fm][fn][r];
  }
  __syncthreads();
  if (wave == 0) {
#pragma unroll
    for (int fm = 0; fm < 2; ++fm)
#pragma unroll
      for (int fn = 0; fn < 2; ++fn)
#pragma unroll
        for (int r = 0; r < 4; ++r) {
          const int row = fm * 16 + l4 * 4 + r, col = fn * 16 + l15;
          float s = acc[fm][fn][r] + red[0][row * 33 + col] + red[1][row * 33 + col] +
                    red[2][row * 33 + col];
          Cb[(size_t)(m0 + row) * 256 + n0 + col] = f2bf(s);
        }
  }
}

// ============ K3: out(1024x1024 f32) = Cb @ Bmat^T + bias =============================
// 256 blocks x 4 waves, each wave one 32x32 tile. XCD-swizzled so the 8 blocks sharing
// a Cb m-slab (p = q+32j, logical b = (p&31)*8 + p>>5, tile = b*4+wave -> m-slab = p&31)
// satisfy p mod 8 == q mod 8 -> same XCD. Round-2-proven body.
__global__ __launch_bounds__(256) void trl_g2(const u16* __restrict__ Cb,
                                              const u16* __restrict__ Bmat,
                                              const float* __restrict__ bias,
                                              float* __restrict__ out) {
  const int tid = threadIdx.x;
  const int wave = tid >> 6, lane = tid & 63;
  const int l15 = lane & 15, l4 = lane >> 4;
  const int p = blockIdx.x;
  const int b = (p & 31) * 8 + (p >> 5);
  const int tile = b * 4 + wave;
  const int m0 = (tile >> 5) * 32, n0 = (tile & 31) * 32;

  f32x4 acc[2][2] = {};
#pragma unroll
  for (int ks = 0; ks < 8; ++ks) {
    const int k = ks * 32 + l4 * 8;
    const bf16x8 a0 = *(const bf16x8*)&Cb[(size_t)(m0 + l15) * 256 + k];
    const bf16x8 a1 = *(const bf16x8*)&Cb[(size_t)(m0 + 16 + l15) * 256 + k];
    const bf16x8 b0 = *(const bf16x8*)&Bmat[(size_t)(n0 + l15) * 256 + k];
    const bf16x8 b1 = *(const bf16x8*)&Bmat[(size_t)(n0 + 16 + l15) * 256 + k];
    acc[0][0] = __builtin_amdgcn_mfma_f32_16x16x32_bf16(a0, b0, acc[0][0], 0, 0, 0);
    acc[0][1] = __builtin_amdgcn_mfma_f32_16x16x32_bf16(a0, b1, acc[0][1], 0, 0, 0);
    acc[1][0] = __builtin_amdgcn_mfma_f32_16x16x32_bf16(a1, b0, acc[1][0], 0, 0, 0);
    acc[1][1] = __builtin_amdgcn_mfma_f32_16x16x32_bf16(a1, b1, acc[1][1], 0, 0, 0);
  }
#pragma unroll
  for (int fn = 0; fn < 2; ++fn) {
    const int gc = n0 + fn * 16 + l15;
    const float bv = bias[gc];
#pragma unroll
    for (int fm = 0; fm < 2; ++fm)
#pragma unroll
      for (int r = 0; r < 4; ++r) {
        const int gr = m0 + fm * 16 + l4 * 4 + r;
        out[(size_t)gr * 1024 + gc] = acc[fm][fn][r] + bv;
      }
  }
}

extern "C" void kernel_launch(void* const* d_in, const int* in_sizes, int n_in,
                              void* d_out, int out_size, void* d_ws, size_t ws_size,
                              hipStream_t stream) {
  const float* x  = (const float*)d_in[0];
  const float* W0 = (const float*)d_in[1];
  const float* W1 = (const float*)d_in[2];
  const float* W2 = (const float*)d_in[3];
  const float* W3 = (const float*)d_in[4];
  const float* W4 = (const float*)d_in[5];
  const float* W5 = (const float*)d_in[6];
  const float* W6 = (const float*)d_in[7];
  const float* W7 = (const float*)d_in[8];
  const float* bias = (const float*)d_in[9];

  char* ws = (char*)d_ws;
  u16* Apre = (u16*)(ws);                   // 512 KB (256x1024 bf16)
  u16* Bmat = (u16*)(ws + (512 << 10));     // 512 KB (1024x256 bf16)
  u16* Cb   = (u16*)(ws + (1024 << 10));    // 512 KB (1024x256 bf16)
  float* outp = (float*)d_out;

  trl_w<<<128, 256, 0, stream>>>(W0, W1, W2, W3, W4, W5, W6, W7, Apre, Bmat);
  trl_g1<<<256, 256, 0, stream>>>(x, Apre, Cb);
  trl_g2<<<256, 256, 0, stream>>>(Cb, Bmat, bias, outp);
}